// Round 1
// baseline (1974.422 us; speedup 1.0000x reference)
//
#include <hip/hip_runtime.h>

#define B_ 32
#define T_ 4096
#define CR 64
#define CS 256
#define NL 20

typedef __bf16 bf16x8 __attribute__((ext_vector_type(8)));
typedef __bf16 bf16x4v __attribute__((ext_vector_type(4)));
typedef float f32x4 __attribute__((ext_vector_type(4)));

__device__ __forceinline__ f32x4 mfma16(bf16x8 a, bf16x8 b, f32x4 c) {
  return __builtin_amdgcn_mfma_f32_16x16x32_bf16(a, b, c, 0, 0, 0);
}

// ---------------- weight pack: fp32 -> bf16, MFMA-A-friendly layouts -------
// WfP/WgP: [i][c_out][tap*64+ci]  (tap0 = delayed tap, k=0 in conv)
// WrP:     [i][c_out][ci]
// WsP:     [cs][i*64+c]   (K=1280 packed for the big skip GEMM)
// bsS:     sum_i b_s[i][cs]
__global__ void pack_kernel(const float* __restrict__ wf, const float* __restrict__ wg,
                            const float* __restrict__ wsn, const float* __restrict__ wr,
                            const float* __restrict__ bs,
                            __bf16* __restrict__ WfP, __bf16* __restrict__ WgP,
                            __bf16* __restrict__ WsP, __bf16* __restrict__ WrP,
                            float* __restrict__ bsS) {
  int n = blockIdx.x * 256 + threadIdx.x;
  if (n < 163840) {
    int ci = n & 63, tap = (n >> 6) & 1, c = (n >> 7) & 63, i = n >> 13;
    WfP[n] = (__bf16)wf[(i * 4096 + c * 64 + ci) * 2 + tap];
  } else if (n < 327680) {
    int m = n - 163840;
    int ci = m & 63, tap = (m >> 6) & 1, c = (m >> 7) & 63, i = m >> 13;
    WgP[m] = (__bf16)wg[(i * 4096 + c * 64 + ci) * 2 + tap];
  } else if (n < 409600) {
    int m = n - 327680;
    WrP[m] = (__bf16)wr[m];  // [i][c][ci] == source layout
  } else if (n < 737280) {
    int m = n - 409600;
    int kk = m % 1280, cs = m / 1280;
    int i = kk >> 6, c = kk & 63;
    WsP[m] = (__bf16)wsn[i * 16384 + cs * 64 + c];
  } else if (n < 737536) {
    int cs = n - 737280;
    float s = 0.f;
    for (int i = 0; i < NL; ++i) s += bs[i * 256 + cs];
    bsS[cs] = s;
  }
}

// ---------------- input 1x1 conv: x[b][ci][t] -> h0[b][t][c] fp32 ----------
__global__ void inconv_kernel(const float* __restrict__ x, const float* __restrict__ w_in,
                              const float* __restrict__ b_in, float* __restrict__ h0) {
  __shared__ float w[64][8];
  __shared__ float bi[64];
  int tid = threadIdx.x;
  for (int k = tid; k < 512; k += 256) w[k >> 3][k & 7] = w_in[k];
  if (tid < 64) bi[tid] = b_in[tid];
  __syncthreads();
  int b = blockIdx.x >> 4;
  int t = ((blockIdx.x & 15) << 8) + tid;
  float xv[8];
#pragma unroll
  for (int ci = 0; ci < 8; ++ci) xv[ci] = x[((size_t)b * 8 + ci) * T_ + t];
  float* orow = h0 + ((size_t)b * T_ + t) * 64;
#pragma unroll
  for (int c0 = 0; c0 < 64; c0 += 4) {
    float s0 = bi[c0], s1 = bi[c0 + 1], s2 = bi[c0 + 2], s3 = bi[c0 + 3];
#pragma unroll
    for (int ci = 0; ci < 8; ++ci) {
      s0 += w[c0][ci] * xv[ci];
      s1 += w[c0 + 1][ci] * xv[ci];
      s2 += w[c0 + 2][ci] * xv[ci];
      s3 += w[c0 + 3][ci] * xv[ci];
    }
    float4 o = make_float4(s0, s1, s2, s3);
    *(float4*)(orow + c0) = o;
  }
}

// ---------------- one gated residual layer --------------------------------
// h_in/h_out: [b][t][64] fp32 (transposed layout). Zg: [b][t][Gs][64] bf16.
__global__ __launch_bounds__(256) void layer_kernel(
    const float* __restrict__ h_in, float* __restrict__ h_out,
    const __bf16* __restrict__ Wf, const __bf16* __restrict__ Wg,
    const __bf16* __restrict__ Wr,
    const float* __restrict__ bF, const float* __restrict__ bG,
    const float* __restrict__ bR,
    __bf16* __restrict__ Zg, int d, int il, int Gs) {
  __shared__ __bf16 sB[2][64][72];  // [0]=delayed tap tile, [1]=current, pitch 72 (144B, 16B-mult)
  __shared__ __bf16 sZ[64][72];
  __shared__ float sH[64][68];  // fp32 residual base

  const int tid = threadIdx.x;
  const int b = blockIdx.x >> 6;
  const int t0 = (blockIdx.x & 63) << 6;
  const float* hbase = h_in + ((size_t)b * T_ + t0) * 64;

#pragma unroll
  for (int it = 0; it < 4; ++it) {
    int f = (it * 256 + tid) * 4;  // flat fp32 index into 64x64 tile
    int tr = f >> 6, c = f & 63;
    float4 v = *(const float4*)(hbase + tr * 64 + c);
    *(float4*)&sH[tr][c] = v;
    bf16x4v pc = {(__bf16)v.x, (__bf16)v.y, (__bf16)v.z, (__bf16)v.w};
    *(bf16x4v*)&sB[1][tr][c] = pc;
    int td = t0 + tr - d;
    float4 u = make_float4(0.f, 0.f, 0.f, 0.f);
    if (td >= 0) u = *(const float4*)(h_in + ((size_t)b * T_ + td) * 64 + c);
    bf16x4v pd = {(__bf16)u.x, (__bf16)u.y, (__bf16)u.z, (__bf16)u.w};
    *(bf16x4v*)&sB[0][tr][c] = pd;
  }
  __syncthreads();

  const int lane = tid & 63, wid = tid >> 6;
  const int tl = (wid << 4) | (lane & 15);  // this wave's time rows (n index)
  const int kq = lane >> 4;                  // k-quad

  bf16x8 bh[4];
  bh[0] = *(const bf16x8*)&sB[0][tl][kq * 8];
  bh[1] = *(const bf16x8*)&sB[0][tl][32 + kq * 8];
  bh[2] = *(const bf16x8*)&sB[1][tl][kq * 8];
  bh[3] = *(const bf16x8*)&sB[1][tl][32 + kq * 8];

#pragma unroll
  for (int mt = 0; mt < 4; ++mt) {
    const int cb = (mt << 4) + (lane & 15);  // A-frag row (c_out)
    f32x4 aF = {0.f, 0.f, 0.f, 0.f}, aG = {0.f, 0.f, 0.f, 0.f};
#pragma unroll
    for (int kc = 0; kc < 4; ++kc) {
      bf16x8 af = *(const bf16x8*)(Wf + cb * 128 + kc * 32 + kq * 8);
      aF = mfma16(af, bh[kc], aF);
      bf16x8 ag = *(const bf16x8*)(Wg + cb * 128 + kc * 32 + kq * 8);
      aG = mfma16(ag, bh[kc], aG);
    }
    const int c0 = (mt << 4) + (kq << 2);  // C/D rows for this lane
    float4 bfv = *(const float4*)(bF + c0);
    float4 bgv = *(const float4*)(bG + c0);
    float fb[4] = {bfv.x, bfv.y, bfv.z, bfv.w};
    float gb[4] = {bgv.x, bgv.y, bgv.z, bgv.w};
    bf16x4v zv;
#pragma unroll
    for (int r = 0; r < 4; ++r) {
      float fp = aF[r] + fb[r];
      float gp = aG[r] + gb[r];
      float e = __expf(2.f * fp);
      float th = 1.f - 2.f / (e + 1.f);        // tanh, inf-safe
      float sg = 1.f / (1.f + __expf(-gp));    // sigmoid
      zv[r] = (__bf16)(th * sg);
    }
    *(bf16x4v*)&sZ[tl][c0] = zv;
  }

  // residual GEMM: reads only this wave's sZ rows (no cross-wave dep)
  bf16x8 bz0 = *(const bf16x8*)&sZ[tl][kq * 8];
  bf16x8 bz1 = *(const bf16x8*)&sZ[tl][32 + kq * 8];
#pragma unroll
  for (int mt = 0; mt < 4; ++mt) {
    const int cb = (mt << 4) + (lane & 15);
    f32x4 aR = {0.f, 0.f, 0.f, 0.f};
    aR = mfma16(*(const bf16x8*)(Wr + cb * 64 + kq * 8), bz0, aR);
    aR = mfma16(*(const bf16x8*)(Wr + cb * 64 + 32 + kq * 8), bz1, aR);
    const int c0 = (mt << 4) + (kq << 2);
    float4 hv = *(const float4*)&sH[tl][c0];
    float4 brv = *(const float4*)(bR + c0);
    float4 o;
    o.x = hv.x + aR[0] + brv.x;
    o.y = hv.y + aR[1] + brv.y;
    o.z = hv.z + aR[2] + brv.z;
    o.w = hv.w + aR[3] + brv.w;
    *(float4*)(h_out + ((size_t)b * T_ + t0 + tl) * 64 + c0) = o;
  }

  __syncthreads();
  // cooperative Z tile writeout: [b][t][il][64] bf16
  {
    int tr = tid >> 2, ch = (tid & 3) << 4;
    const uint4 v0 = *(const uint4*)&sZ[tr][ch];
    const uint4 v1 = *(const uint4*)&sZ[tr][ch + 8];
    __bf16* dst = Zg + (((size_t)b * T_ + t0 + tr) * Gs + il) * 64 + ch;
    *(uint4*)dst = v0;
    *(uint4*)(dst + 8) = v1;
  }
}

// ---------------- grouped skip GEMM: out[b][cs][t] (+)= Z . Ws^T ----------
__global__ __launch_bounds__(256) void skip_kernel(
    const __bf16* __restrict__ Zg, const __bf16* __restrict__ WsP,
    const float* __restrict__ bsS, float* __restrict__ out,
    int i0, int cnt, int Gs, int first) {
  const int tid = threadIdx.x;
  const int b = blockIdx.x >> 6;
  const int t0 = (blockIdx.x & 63) << 6;
  const int lane = tid & 63, wid = tid >> 6;
  const int tl = (wid << 4) | (lane & 15);
  const int kq = lane >> 4;

  f32x4 acc[16];
#pragma unroll
  for (int mt = 0; mt < 16; ++mt) acc[mt] = (f32x4){0.f, 0.f, 0.f, 0.f};

  const __bf16* zrow = Zg + ((size_t)b * T_ + t0 + tl) * Gs * 64;
  for (int il = 0; il < cnt; ++il) {
    bf16x8 b0 = *(const bf16x8*)(zrow + il * 64 + kq * 8);
    bf16x8 b1 = *(const bf16x8*)(zrow + il * 64 + 32 + kq * 8);
    const __bf16* Abase = WsP + (i0 + il) * 64 + kq * 8;
#pragma unroll
    for (int mt = 0; mt < 16; ++mt) {
      const int cs = (mt << 4) + (lane & 15);
      acc[mt] = mfma16(*(const bf16x8*)(Abase + cs * 1280), b0, acc[mt]);
      acc[mt] = mfma16(*(const bf16x8*)(Abase + cs * 1280 + 32), b1, acc[mt]);
    }
  }

#pragma unroll
  for (int mt = 0; mt < 16; ++mt) {
#pragma unroll
    for (int r = 0; r < 4; ++r) {
      int cs = (mt << 4) + (kq << 2) + r;
      size_t idx = ((size_t)b * CS + cs) * T_ + t0 + tl;
      float v = acc[mt][r];
      if (first) {
        out[idx] = v + bsS[cs];
      } else {
        out[idx] += v;
      }
    }
  }
}

extern "C" void kernel_launch(void* const* d_in, const int* in_sizes, int n_in,
                              void* d_out, int out_size, void* d_ws, size_t ws_size,
                              hipStream_t stream) {
  (void)in_sizes; (void)n_in; (void)out_size;
  const float* x    = (const float*)d_in[0];
  const float* w_in = (const float*)d_in[1];
  const float* b_in = (const float*)d_in[2];
  const float* w_f  = (const float*)d_in[3];
  const float* b_f  = (const float*)d_in[4];
  const float* w_g  = (const float*)d_in[5];
  const float* b_g  = (const float*)d_in[6];
  const float* w_s  = (const float*)d_in[7];
  const float* b_s  = (const float*)d_in[8];
  const float* w_r  = (const float*)d_in[9];
  const float* b_r  = (const float*)d_in[10];
  float* out = (float*)d_out;

  char* ws = (char*)d_ws;
  size_t off = 0;
  auto alloc = [&](size_t bytes) -> char* {
    char* p = ws + off;
    off = (off + bytes + 255) & ~(size_t)255;
    return p;
  };
  float* hA = (float*)alloc((size_t)B_ * T_ * 64 * 4);      // 32 MB
  float* hB = (float*)alloc((size_t)B_ * T_ * 64 * 4);      // 32 MB
  __bf16* WfP = (__bf16*)alloc((size_t)NL * 64 * 128 * 2);
  __bf16* WgP = (__bf16*)alloc((size_t)NL * 64 * 128 * 2);
  __bf16* WrP = (__bf16*)alloc((size_t)NL * 64 * 64 * 2);
  __bf16* WsP = (__bf16*)alloc((size_t)CS * NL * 64 * 2);
  float* bsS = (float*)alloc(CS * 4);

  size_t zslot = (size_t)B_ * T_ * 64 * 2;  // 16 MB per layer slot
  size_t rem = (ws_size > off) ? (ws_size - off) : 0;
  int G = (int)(rem / zslot);
  if (G > NL) G = NL;
  if (G < 1) G = 1;  // minimum-footprint fallback
  __bf16* Zg = (__bf16*)(ws + off);

  hipLaunchKernelGGL(pack_kernel, dim3(2881), dim3(256), 0, stream,
                     w_f, w_g, w_s, w_r, b_s, WfP, WgP, WsP, WrP, bsS);
  hipLaunchKernelGGL(inconv_kernel, dim3(512), dim3(256), 0, stream, x, w_in, b_in, hA);

  float* hc = hA;
  float* hn = hB;
  int i0 = 0;
  for (int i = 0; i < NL; ++i) {
    int il = i - i0;
    hipLaunchKernelGGL(layer_kernel, dim3(B_ * 64), dim3(256), 0, stream,
                       hc, hn, WfP + i * 8192, WgP + i * 8192, WrP + i * 4096,
                       b_f + i * 64, b_g + i * 64, b_r + i * 64,
                       Zg, 1 << (i % 10), il, G);
    { float* tmp = hc; hc = hn; hn = tmp; }
    if (il + 1 == G || i == NL - 1) {
      int cnt = il + 1;
      hipLaunchKernelGGL(skip_kernel, dim3(B_ * 64), dim3(256), 0, stream,
                         Zg, WsP, bsS, out, i0, cnt, G, (i0 == 0) ? 1 : 0);
      i0 = i + 1;
    }
  }
}

// Round 2
// 1004.264 us; speedup vs baseline: 1.9660x; 1.9660x over previous
//
#include <hip/hip_runtime.h>

#define B_ 32
#define T_ 4096
#define CR 64
#define CS 256
#define NL 20

typedef __bf16 bf16x8 __attribute__((ext_vector_type(8)));
typedef __bf16 bf16x4v __attribute__((ext_vector_type(4)));
typedef float f32x4 __attribute__((ext_vector_type(4)));

__device__ __forceinline__ f32x4 mfma16(bf16x8 a, bf16x8 b, f32x4 c) {
  return __builtin_amdgcn_mfma_f32_16x16x32_bf16(a, b, c, 0, 0, 0);
}

// ---------------- weight pack: fp32 -> bf16, fragment-linear layouts ------
// All packed so one wave's 16B/lane A-frag load is 1KB fully contiguous.
// A-frag semantics: lane l supplies A[m=l&15][k=(l>>4)*8+j].
// Wfg2: [i][mt(4)][fr(8: 0-3=f kc, 4-7=g kc)][lane(64)][8]   (K = tap*64+ci)
// Wr2:  [i][mt(4)][kc(2)][lane(64)][8]                        (K = ci)
// Ws2:  [i][tile(16)][kc(2)][lane(64)][8]                     (K = ci)
// bsS:  sum_i b_s[i][cs]
__global__ void pack_kernel(const float* __restrict__ wf, const float* __restrict__ wg,
                            const float* __restrict__ wsn, const float* __restrict__ wr,
                            const float* __restrict__ bs,
                            __bf16* __restrict__ Wfg2, __bf16* __restrict__ Wr2,
                            __bf16* __restrict__ Ws2, float* __restrict__ bsS) {
  int n = blockIdx.x * 256 + threadIdx.x;
  if (n < 327680) {
    int j = n & 7, lane = (n >> 3) & 63, fr = (n >> 9) & 7, mt = (n >> 12) & 3, i = n >> 14;
    int cs = mt * 16 + (lane & 15);
    int k = (fr & 3) * 32 + (lane >> 4) * 8 + j;
    int ci = k & 63, tap = k >> 6;  // tap0 = delayed tap (conv k=0)
    const float* src = (fr < 4) ? wf : wg;
    Wfg2[n] = (__bf16)src[((i * 64 + cs) * 64 + ci) * 2 + tap];
  } else if (n < 409600) {
    int m = n - 327680;
    int j = m & 7, lane = (m >> 3) & 63, kc = (m >> 9) & 1, mt = (m >> 10) & 3, i = m >> 12;
    int cs = mt * 16 + (lane & 15);
    int ci = kc * 32 + (lane >> 4) * 8 + j;
    Wr2[m] = (__bf16)wr[(i * 64 + cs) * 64 + ci];
  } else if (n < 737280) {
    int m = n - 409600;
    int j = m & 7, lane = (m >> 3) & 63, kc = (m >> 9) & 1, tile = (m >> 10) & 15, i = m >> 14;
    int cs = tile * 16 + (lane & 15);
    int ci = kc * 32 + (lane >> 4) * 8 + j;
    Ws2[m] = (__bf16)wsn[i * 16384 + cs * 64 + ci];
  } else if (n < 737536) {
    int cs = n - 737280;
    float s = 0.f;
    for (int i = 0; i < NL; ++i) s += bs[i * 256 + cs];
    bsS[cs] = s;
  }
}

// ---------------- input 1x1 conv: x[b][ci][t] -> h0[b][t][c] fp32 ----------
__global__ void inconv_kernel(const float* __restrict__ x, const float* __restrict__ w_in,
                              const float* __restrict__ b_in, float* __restrict__ h0) {
  __shared__ float w[64][8];
  __shared__ float bi[64];
  int tid = threadIdx.x;
  for (int k = tid; k < 512; k += 256) w[k >> 3][k & 7] = w_in[k];
  if (tid < 64) bi[tid] = b_in[tid];
  __syncthreads();
  int b = blockIdx.x >> 4;
  int t = ((blockIdx.x & 15) << 8) + tid;
  float xv[8];
#pragma unroll
  for (int ci = 0; ci < 8; ++ci) xv[ci] = x[((size_t)b * 8 + ci) * T_ + t];
  float* orow = h0 + ((size_t)b * T_ + t) * 64;
#pragma unroll
  for (int c0 = 0; c0 < 64; c0 += 4) {
    float s0 = bi[c0], s1 = bi[c0 + 1], s2 = bi[c0 + 2], s3 = bi[c0 + 3];
#pragma unroll
    for (int ci = 0; ci < 8; ++ci) {
      s0 += w[c0][ci] * xv[ci];
      s1 += w[c0 + 1][ci] * xv[ci];
      s2 += w[c0 + 2][ci] * xv[ci];
      s3 += w[c0 + 3][ci] * xv[ci];
    }
    float4 o = make_float4(s0, s1, s2, s3);
    *(float4*)(orow + c0) = o;
  }
}

// ---------------- one gated residual layer --------------------------------
// h_in/h_out: [b][t][64] fp32. Zg: [b][t][slot][64] bf16.
// LDS: sB[0]=delayed tap tile (reused as sZ after frags consumed), sB[1]=cur.
__global__ __launch_bounds__(256) void layer_kernel(
    const float* __restrict__ h_in, float* __restrict__ h_out,
    const __bf16* __restrict__ Wfg, const __bf16* __restrict__ Wr,
    const float* __restrict__ bF, const float* __restrict__ bG,
    const float* __restrict__ bR,
    __bf16* __restrict__ Zg, int d, int il, int Gs) {
  __shared__ __bf16 sB[2][64][72];  // pitch 72 elem = 144B

  const int tid = threadIdx.x;
  const int b = blockIdx.x >> 6;
  const int t0 = (blockIdx.x & 63) << 6;
  const float* hbase = h_in + ((size_t)b * T_ + t0) * 64;

#pragma unroll
  for (int it = 0; it < 4; ++it) {
    int f = (it * 256 + tid) * 4;  // flat fp32 index into 64x64 tile
    int tr = f >> 6, c = f & 63;
    float4 v = *(const float4*)(hbase + tr * 64 + c);
    bf16x4v pc = {(__bf16)v.x, (__bf16)v.y, (__bf16)v.z, (__bf16)v.w};
    *(bf16x4v*)&sB[1][tr][c] = pc;
    int td = t0 + tr - d;
    float4 u = make_float4(0.f, 0.f, 0.f, 0.f);
    if (td >= 0) u = *(const float4*)(h_in + ((size_t)b * T_ + td) * 64 + c);
    bf16x4v pd = {(__bf16)u.x, (__bf16)u.y, (__bf16)u.z, (__bf16)u.w};
    *(bf16x4v*)&sB[0][tr][c] = pd;
  }
  __syncthreads();

  const int lane = tid & 63, wid = tid >> 6;
  const int tl = (wid << 4) | (lane & 15);  // this wave's time rows (n index)
  const int kq = lane >> 4;

  bf16x8 bh[4];  // K = tap*64 + ci: kc0,1 = delayed, kc2,3 = current
  bh[0] = *(const bf16x8*)&sB[0][tl][kq * 8];
  bh[1] = *(const bf16x8*)&sB[0][tl][32 + kq * 8];
  bh[2] = *(const bf16x8*)&sB[1][tl][kq * 8];
  bh[3] = *(const bf16x8*)&sB[1][tl][32 + kq * 8];

  __bf16 (*sZ)[72] = sB[0];  // overlay: each wave reads/writes only its own rows

#pragma unroll
  for (int mt = 0; mt < 4; ++mt) {
    const __bf16* wb = Wfg + (mt * 8) * 512 + lane * 8;
    f32x4 aF = {0.f, 0.f, 0.f, 0.f}, aG = {0.f, 0.f, 0.f, 0.f};
#pragma unroll
    for (int kc = 0; kc < 4; ++kc) {
      aF = mfma16(*(const bf16x8*)(wb + kc * 512), bh[kc], aF);
      aG = mfma16(*(const bf16x8*)(wb + (4 + kc) * 512), bh[kc], aG);
    }
    const int c0 = (mt << 4) + (kq << 2);  // C/D rows (c_out) for this lane
    float4 bfv = *(const float4*)(bF + c0);
    float4 bgv = *(const float4*)(bG + c0);
    float fb[4] = {bfv.x, bfv.y, bfv.z, bfv.w};
    float gb[4] = {bgv.x, bgv.y, bgv.z, bgv.w};
    bf16x4v zv;
#pragma unroll
    for (int r = 0; r < 4; ++r) {
      float fp = aF[r] + fb[r];
      float gp = aG[r] + gb[r];
      float e = __expf(2.f * fp);
      float th = 1.f - 2.f / (e + 1.f);      // tanh, inf-safe
      float sg = 1.f / (1.f + __expf(-gp));  // sigmoid
      zv[r] = (__bf16)(th * sg);
    }
    *(bf16x4v*)&sZ[tl][c0] = zv;
  }

  // residual GEMM: wave-private rows of sZ
  bf16x8 bz0 = *(const bf16x8*)&sZ[tl][kq * 8];
  bf16x8 bz1 = *(const bf16x8*)&sZ[tl][32 + kq * 8];
#pragma unroll
  for (int mt = 0; mt < 4; ++mt) {
    const __bf16* wrb = Wr + (mt * 2) * 512 + lane * 8;
    f32x4 aR = {0.f, 0.f, 0.f, 0.f};
    aR = mfma16(*(const bf16x8*)(wrb), bz0, aR);
    aR = mfma16(*(const bf16x8*)(wrb + 512), bz1, aR);
    const int c0 = (mt << 4) + (kq << 2);
    float4 hv = *(const float4*)(h_in + ((size_t)b * T_ + t0 + tl) * 64 + c0);  // L1/L2 hot
    float4 brv = *(const float4*)(bR + c0);
    float4 o;
    o.x = hv.x + aR[0] + brv.x;
    o.y = hv.y + aR[1] + brv.y;
    o.z = hv.z + aR[2] + brv.z;
    o.w = hv.w + aR[3] + brv.w;
    *(float4*)(h_out + ((size_t)b * T_ + t0 + tl) * 64 + c0) = o;
  }

  __syncthreads();
  // cooperative Z tile writeout: [b][t][slot][64] bf16
  {
    int tr = tid >> 2, ch = (tid & 3) << 4;
    const uint4 v0 = *(const uint4*)&sZ[tr][ch];
    const uint4 v1 = *(const uint4*)&sZ[tr][ch + 8];
    __bf16* dst = Zg + (((size_t)b * T_ + t0 + tr) * Gs + il) * 64 + ch;
    *(uint4*)dst = v0;
    *(uint4*)(dst + 8) = v1;
  }
}

// ---------------- grouped skip GEMM: out[b][cs][t] (+)= Z . Ws^T ----------
// Block: 64-t tile x all 256 cs. Wave w: cs in [64w, 64w+64).
// Z staged in LDS (double-buffered); W frags coalesced 1KB loads, prefetched.
__global__ __launch_bounds__(256) void skip_kernel(
    const __bf16* __restrict__ Zg, const __bf16* __restrict__ Ws2,
    const float* __restrict__ bsS, float* __restrict__ out,
    int i0, int cnt, int Gs, int first) {
  __shared__ __bf16 sZ[2][64][72];

  const int tid = threadIdx.x;
  const int b = blockIdx.x >> 6;
  const int t0 = (blockIdx.x & 63) << 6;
  const int lane = tid & 63, wid = tid >> 6;
  const int kq = lane >> 4;
  const int tr = tid >> 2, coff = (tid & 3) << 4;  // staging: 32B/thread

  const __bf16* zbase = Zg + (((size_t)b * T_ + t0 + tr) * Gs) * 64 + coff;
  const __bf16* wbase = Ws2 + (size_t)i0 * 16384 + (size_t)(wid * 8) * 512 + lane * 8;

  // prologue: stage Z(0), load W(0) frags
  {
    uint4 z0 = *(const uint4*)zbase;
    uint4 z1 = *(const uint4*)(zbase + 8);
    *(uint4*)&sZ[0][tr][coff] = z0;
    *(uint4*)&sZ[0][tr][coff + 8] = z1;
  }
  bf16x8 aw[8];
#pragma unroll
  for (int f = 0; f < 8; ++f) aw[f] = *(const bf16x8*)(wbase + f * 512);

  f32x4 acc[16];
#pragma unroll
  for (int q = 0; q < 16; ++q) acc[q] = (f32x4){0.f, 0.f, 0.f, 0.f};

  __syncthreads();

  const char* zrow0 = (const char*)&sZ[0][0][0] + (lane & 15) * 144 + kq * 16;

  for (int il = 0; il < cnt; ++il) {
    const int cur = il & 1;
    bf16x8 bz[8];
#pragma unroll
    for (int nt = 0; nt < 4; ++nt) {
      bz[nt * 2]     = *(const bf16x8*)(zrow0 + cur * 9216 + nt * 2304);
      bz[nt * 2 + 1] = *(const bf16x8*)(zrow0 + cur * 9216 + nt * 2304 + 64);
    }
    uint4 p0, p1;
    bf16x8 awn[8];
    const bool more = (il + 1) < cnt;
    if (more) {
      p0 = *(const uint4*)(zbase + (il + 1) * 64);
      p1 = *(const uint4*)(zbase + (il + 1) * 64 + 8);
#pragma unroll
      for (int f = 0; f < 8; ++f)
        awn[f] = *(const bf16x8*)(wbase + (size_t)(il + 1) * 16384 + f * 512);
    }
#pragma unroll
    for (int mt = 0; mt < 4; ++mt) {
#pragma unroll
      for (int nt = 0; nt < 4; ++nt) {
        acc[mt * 4 + nt] = mfma16(aw[mt * 2], bz[nt * 2], acc[mt * 4 + nt]);
        acc[mt * 4 + nt] = mfma16(aw[mt * 2 + 1], bz[nt * 2 + 1], acc[mt * 4 + nt]);
      }
    }
    if (more) {
      *(uint4*)&sZ[cur ^ 1][tr][coff] = p0;
      *(uint4*)&sZ[cur ^ 1][tr][coff + 8] = p1;
#pragma unroll
      for (int f = 0; f < 8; ++f) aw[f] = awn[f];
      __syncthreads();  // single barrier/stage: write(nxt) before B; read(cur) after prev B
    }
  }

  const int csb = wid * 64 + (kq << 2);
  const int tcol = t0 + (lane & 15);
#pragma unroll
  for (int mt = 0; mt < 4; ++mt) {
#pragma unroll
    for (int nt = 0; nt < 4; ++nt) {
#pragma unroll
      for (int r = 0; r < 4; ++r) {
        int cs = csb + mt * 16 + r;
        size_t idx = ((size_t)b * CS + cs) * T_ + tcol + nt * 16;
        float v = acc[mt * 4 + nt][r];
        if (first) out[idx] = v + bsS[cs];
        else out[idx] += v;
      }
    }
  }
}

extern "C" void kernel_launch(void* const* d_in, const int* in_sizes, int n_in,
                              void* d_out, int out_size, void* d_ws, size_t ws_size,
                              hipStream_t stream) {
  (void)in_sizes; (void)n_in; (void)out_size;
  const float* x    = (const float*)d_in[0];
  const float* w_in = (const float*)d_in[1];
  const float* b_in = (const float*)d_in[2];
  const float* w_f  = (const float*)d_in[3];
  const float* b_f  = (const float*)d_in[4];
  const float* w_g  = (const float*)d_in[5];
  const float* b_g  = (const float*)d_in[6];
  const float* w_s  = (const float*)d_in[7];
  const float* b_s  = (const float*)d_in[8];
  const float* w_r  = (const float*)d_in[9];
  const float* b_r  = (const float*)d_in[10];
  float* out = (float*)d_out;

  char* ws = (char*)d_ws;
  size_t off = 0;
  auto alloc = [&](size_t bytes) -> char* {
    char* p = ws + off;
    off = (off + bytes + 255) & ~(size_t)255;
    return p;
  };
  float* hA = (float*)alloc((size_t)B_ * T_ * 64 * 4);      // 32 MB
  float* hB = (float*)alloc((size_t)B_ * T_ * 64 * 4);      // 32 MB
  __bf16* Wfg2 = (__bf16*)alloc((size_t)NL * 16384 * 2);
  __bf16* Wr2  = (__bf16*)alloc((size_t)NL * 4096 * 2);
  __bf16* Ws2  = (__bf16*)alloc((size_t)NL * 16384 * 2);
  float* bsS = (float*)alloc(CS * 4);

  size_t zslot = (size_t)B_ * T_ * 64 * 2;  // 16 MB per layer slot
  size_t rem = (ws_size > off) ? (ws_size - off) : 0;
  int G = (int)(rem / zslot);
  if (G > NL) G = NL;
  if (G < 1) G = 1;
  __bf16* Zg = (__bf16*)(ws + off);

  hipLaunchKernelGGL(pack_kernel, dim3(2881), dim3(256), 0, stream,
                     w_f, w_g, w_s, w_r, b_s, Wfg2, Wr2, Ws2, bsS);
  hipLaunchKernelGGL(inconv_kernel, dim3(512), dim3(256), 0, stream, x, w_in, b_in, hA);

  float* hc = hA;
  float* hn = hB;
  int i0 = 0;
  for (int i = 0; i < NL; ++i) {
    int il = i - i0;
    hipLaunchKernelGGL(layer_kernel, dim3(B_ * 64), dim3(256), 0, stream,
                       hc, hn, Wfg2 + (size_t)i * 16384, Wr2 + (size_t)i * 4096,
                       b_f + i * 64, b_g + i * 64, b_r + i * 64,
                       Zg, 1 << (i % 10), il, G);
    { float* tmp = hc; hc = hn; hn = tmp; }
    if (il + 1 == G || i == NL - 1) {
      int cnt = il + 1;
      hipLaunchKernelGGL(skip_kernel, dim3(B_ * 64), dim3(256), 0, stream,
                         Zg, Ws2, bsS, out, i0, cnt, G, (i0 == 0) ? 1 : 0);
      i0 = i + 1;
    }
  }
}